// Round 1
// baseline (1915.343 us; speedup 1.0000x reference)
//
#include <hip/hip_runtime.h>
#include <math.h>

// Problem constants (N,C,H,W) = (8,64,256,256)
constexpr int Nn  = 8;
constexpr int Cc  = 64;
constexpr int HWp = 65536;           // H*W
constexpr int TPB = 256;             // threads per block
constexpr int PPT = 4;               // pixels per thread in heavy kernels
constexpr int PIXB = TPB * PPT;      // 1024 pixels per block
constexpr int CHUNKS = HWp / PIXB;   // 64 -> 1024 blocks for heavy kernels

// ---------- helpers ----------
__device__ inline unsigned fkey(float f) {
  unsigned u = __float_as_uint(f);
  return (u & 0x80000000u) ? ~u : (u | 0x80000000u);  // order-preserving float->uint
}
__device__ inline float funkey(unsigned k) {
  return __uint_as_float((k & 0x80000000u) ? (k & 0x7fffffffu) : ~k);
}
__device__ inline float wmax(float v) {
#pragma unroll
  for (int m = 32; m; m >>= 1) v = fmaxf(v, __shfl_xor(v, m, 64));
  return v;
}
__device__ inline float wsum(float v) {
#pragma unroll
  for (int m = 32; m; m >>= 1) v += __shfl_xor(v, m, 64);
  return v;
}
__device__ inline float silu_(float z) { return z / (1.f + __expf(-z)); }

// ---------- k1: per-pixel conv MAX over pixels + key pre-softmax ----------
// (sum/mean path removed: it is linear, computed from per-channel sums S in k2/k3)
// Live set ~ xv[64] + mx[64] + ~15 ≈ 145 VGPR. waves_per_eu(2,3) => budget >= 170,
// no spill-for-occupancy (the old (TPB,2) build spilled: 104 VGPR, +36MB scratch writes).
__global__ __launch_bounds__(TPB) __attribute__((amdgpu_waves_per_eu(2, 3)))
void k1_stats(
    const float* __restrict__ xrgb, const float* __restrict__ xir,
    const float* __restrict__ conv_w, const float* __restrict__ conv_b,
    const float* __restrict__ key_w, const float* __restrict__ key_g,
    const float* __restrict__ key_b, const float* __restrict__ key_m,
    const float* __restrict__ key_v,
    float* __restrict__ kpre, unsigned* __restrict__ mxk,
    unsigned* __restrict__ kmaxk)
{
  const int side = blockIdx.z, n = blockIdx.y, chunk = blockIdx.x;
  const float* x = (side ? xir : xrgb) + (size_t)n * Cc * HWp;
  const float ks = key_g[0] * rsqrtf(key_v[0] + 1e-5f);
  const float kb = key_b[0] - key_m[0] * ks;
  float mx[64];
#pragma unroll
  for (int o = 0; o < 64; o++) mx[o] = -1e30f;
  float kml = -1e30f;
  float* kp = kpre + (size_t)(side * Nn + n) * HWp;
  const int e0 = chunk * PIXB + threadIdx.x;
#pragma unroll 1
  for (int i = 0; i < PPT; i++) {
    const int e = e0 + i * TPB;
    float xv[64];
#pragma unroll
    for (int c = 0; c < 64; c++) xv[c] = x[(size_t)c * HWp + e];
    // key conv (1xC) + BN + SiLU
    float kd = 0.f;
#pragma unroll
    for (int c = 0; c < 64; c++) kd += key_w[c] * xv[c];
    float ka = silu_(ks * kd + kb);
    kp[e] = ka;
    kml = fmaxf(kml, ka);
    // main conv: per-o max over pixels
#pragma unroll
    for (int o = 0; o < 64; o++) {
      float acc = conv_b[o];
#pragma unroll
      for (int c = 0; c < 64; c++) acc += conv_w[o * 64 + c] * xv[c];
      mx[o] = fmaxf(mx[o], acc);
    }
  }
  const int lane = threadIdx.x & 63;
  const int base = (side * Nn + n) * 64;
#pragma unroll
  for (int o = 0; o < 64; o++) {
    float m1 = wmax(mx[o]);
    if (lane == 0) atomicMax(&mxk[base + o], fkey(m1));
  }
  float km = wmax(kml);
  if (lane == 0) atomicMax(&kmaxk[side * Nn + n], fkey(km));
}

// ---------- k2: key softmax denominator + per-channel pixel sums S[c] ----------
// Streaming, memory-bound (~260 MB). S feeds the (linear) mean/softmax path in k3.
__global__ __launch_bounds__(TPB) void k2_ksum(
    const float* __restrict__ xrgb, const float* __restrict__ xir,
    const float* __restrict__ kpre, const unsigned* __restrict__ kmaxk,
    float* __restrict__ ksum, float* __restrict__ S)
{
  const int sn = blockIdx.x;           // side*N+n, 0..15
  const int side = sn >> 3, n = sn & 7;
  const float* x = (side ? xir : xrgb) + (size_t)n * Cc * HWp;
  const int lo = blockIdx.y * 2048;    // 32 slices of 2048 pixels
  const int tid = threadIdx.x;
  const int lane = tid & 63;

  // key softmax denominator
  const float kmax = funkey(kmaxk[sn]);
  const float* kp = kpre + (size_t)sn * HWp;
  float s = 0.f;
#pragma unroll
  for (int i = 0; i < 8; i++) s += __expf(kp[lo + i * TPB + tid] - kmax);
  s = wsum(s);
  __shared__ float red[4];
  const int w = tid >> 6;
  if (lane == 0) red[w] = s;
  __syncthreads();
  if (tid == 0) atomicAdd(&ksum[sn], red[0] + red[1] + red[2] + red[3]);

  // per-channel pixel sums
  for (int c = 0; c < 64; c++) {
    float t = 0.f;
#pragma unroll
    for (int i = 0; i < 8; i++) t += x[(size_t)c * HWp + lo + i * TPB + tid];
    t = wsum(t);
    if (lane == 0) atomicAdd(&S[sn * 64 + c], t);
  }
}

// ---------- k3: avg/max softmax over channels + val-BN constants ----------
// mean logits reconstructed algebraically: lm[o] = conv_b[o] + dot(conv_w[o,:], S)/HW
__global__ void k3_fin(const float* __restrict__ S, const unsigned* __restrict__ mxk,
                       const float* __restrict__ conv_w, const float* __restrict__ conv_b,
                       const float* __restrict__ val_g, const float* __restrict__ val_b,
                       const float* __restrict__ val_m, const float* __restrict__ val_v,
                       float* __restrict__ avg, float* __restrict__ mxs,
                       float* __restrict__ vs_arr, float* __restrict__ vb_arr)
{
  const int sn = blockIdx.x, o = threadIdx.x;  // 64 threads = 1 wave
  if (sn == 0) {
    float s = val_g[o] * rsqrtf(val_v[o] + 1e-5f);
    vs_arr[o] = s;
    vb_arr[o] = val_b[o] - val_m[o] * s;
  }
  float z = 0.f;
#pragma unroll
  for (int c = 0; c < 64; c++) z += conv_w[o * 64 + c] * S[sn * 64 + c];
  float lm = conv_b[o] + z * (1.f / HWp);
  float M = wmax(lm);
  float E = __expf(lm - M);
  float Sm = wsum(E);
  avg[sn * 64 + o] = E / Sm;
  float mm = funkey(mxk[sn * 64 + o]);
  M = wmax(mm);
  E = __expf(mm - M);
  Sm = wsum(E);
  mxs[sn * 64 + o] = E / Sm;
}

// ---------- k4: val conv on-the-fly + fea/avgm/maxm contractions + half ----------
// Live set ~ xv[64] + feap[64] + ~15 ≈ 145 VGPR — same no-spill treatment as k1.
__global__ __launch_bounds__(TPB) __attribute__((amdgpu_waves_per_eu(2, 3)))
void k4_val(
    const float* __restrict__ xrgb, const float* __restrict__ xir,
    const float* __restrict__ val_w,
    const float* __restrict__ vs_arr, const float* __restrict__ vb_arr,
    const float* __restrict__ avg, const float* __restrict__ mxs,
    const float* __restrict__ kpre, const unsigned* __restrict__ kmaxk,
    const float* __restrict__ ksum,
    const float* __restrict__ half_w, const float* __restrict__ half_g,
    const float* __restrict__ half_b, const float* __restrict__ half_m,
    const float* __restrict__ half_v,
    float* __restrict__ halfb, float* __restrict__ fea)
{
  const int me = blockIdx.z, n = blockIdx.y, chunk = blockIdx.x;
  // v comes from the OTHER side's features; stats/key/half/fea belong to `me`
  const float* xo = (me ? xrgb : xir) + (size_t)n * Cc * HWp;
  const int sn = me * Nn + n;
  const float kmax = funkey(kmaxk[sn]);
  const float kinv = 1.f / ksum[sn];
  const float* kp = kpre + (size_t)sn * HWp;
  const float hs = half_g[0] * rsqrtf(half_v[0] + 1e-5f);
  const float hb = half_b[0] - half_m[0] * hs;
  const float hw0 = half_w[0], hw1 = half_w[1];
  float* hp = halfb + (size_t)sn * HWp;
  float feap[64];
#pragma unroll
  for (int o = 0; o < 64; o++) feap[o] = 0.f;
  const int e0 = chunk * PIXB + threadIdx.x;
#pragma unroll 1
  for (int i = 0; i < PPT; i++) {
    const int e = e0 + i * TPB;
    float xv[64];
#pragma unroll
    for (int c = 0; c < 64; c++) xv[c] = xo[(size_t)c * HWp + e];
    const float kw = __expf(kp[e] - kmax) * kinv;
    float am = 0.f, mm = 0.f;
#pragma unroll
    for (int o = 0; o < 64; o++) {
      float acc = 0.f;
#pragma unroll
      for (int c = 0; c < 64; c++) acc += val_w[o * 64 + c] * xv[c];
      float v = silu_(vs_arr[o] * acc + vb_arr[o]);
      am += avg[sn * 64 + o] * v;
      mm += mxs[sn * 64 + o] * v;
      feap[o] += v * kw;
    }
    hp[e] = silu_(hs * (hw0 * am + hw1 * mm) + hb);
  }
  const int lane = threadIdx.x & 63;
#pragma unroll
  for (int o = 0; o < 64; o++) {
    float s1 = wsum(feap[o]);
    if (lane == 0) atomicAdd(&fea[sn * 64 + o], s1);
  }
}

// ---------- k5: gate = sigmoid(LN(fea @ convb_w^T)) ----------
__global__ void k5_gate(const float* __restrict__ fea, const float* __restrict__ convb_w,
                        const float* __restrict__ ln_g, const float* __restrict__ ln_b,
                        float* __restrict__ gate)
{
  const int sn = blockIdx.x, o = threadIdx.x;  // 64 threads = 1 wave
  float z = 0.f;
#pragma unroll
  for (int c = 0; c < 64; c++) z += convb_w[o * 64 + c] * fea[sn * 64 + c];
  float mu = wsum(z) * (1.f / 64);
  float d = z - mu;
  float var = wsum(d * d) * (1.f / 64);
  float g = d * rsqrtf(var + 1e-5f) * ln_g[o] + ln_b[o];
  gate[sn * 64 + o] = 1.f / (1.f + __expf(-g));
}

// ---------- k6: out = gate*half + x (streaming, float4) ----------
__global__ __launch_bounds__(256) void k6_out(
    const float* __restrict__ xrgb, const float* __restrict__ xir,
    const float* __restrict__ gate, const float* __restrict__ halfb,
    float* __restrict__ out)
{
  const size_t t = (size_t)blockIdx.x * 256 + threadIdx.x;  // float4 index
  const int e4 = (int)(t & (HWp / 4 - 1));
  size_t r = t >> 14;
  const int c = (int)(r & 63); r >>= 6;
  const int n = (int)(r & 7);
  const int me = (int)(r >> 3);
  const float* x = me ? xir : xrgb;
  const float4 xv = ((const float4*)x)[(((size_t)n * 64 + c) << 14) + e4];
  const float g = gate[(me * 8 + n) * 64 + c];
  const float4 h = ((const float4*)halfb)[((size_t)(me * 8 + n) << 14) + e4];
  float4 ov;
  ov.x = g * h.x + xv.x;
  ov.y = g * h.y + xv.y;
  ov.z = g * h.z + xv.z;
  ov.w = g * h.w + xv.w;
  ((float4*)out)[t] = ov;
}

extern "C" void kernel_launch(void* const* d_in, const int* in_sizes, int n_in,
                              void* d_out, int out_size, void* d_ws, size_t ws_size,
                              hipStream_t stream)
{
  const float* xrgb   = (const float*)d_in[0];
  const float* xir    = (const float*)d_in[1];
  const float* conv_w = (const float*)d_in[2];
  const float* conv_b = (const float*)d_in[3];
  const float* key_w  = (const float*)d_in[4];
  const float* key_g  = (const float*)d_in[5];
  const float* key_b  = (const float*)d_in[6];
  const float* key_m  = (const float*)d_in[7];
  const float* key_v  = (const float*)d_in[8];
  const float* val_w  = (const float*)d_in[9];
  const float* val_g  = (const float*)d_in[10];
  const float* val_b  = (const float*)d_in[11];
  const float* val_m  = (const float*)d_in[12];
  const float* val_v  = (const float*)d_in[13];
  const float* convb_w= (const float*)d_in[14];
  const float* half_w = (const float*)d_in[15];
  const float* half_g = (const float*)d_in[16];
  const float* half_b = (const float*)d_in[17];
  const float* half_m = (const float*)d_in[18];
  const float* half_v = (const float*)d_in[19];
  const float* ln_g   = (const float*)d_in[20];
  const float* ln_b   = (const float*)d_in[21];

  // workspace layout (floats): ~8.4 MiB total
  float* ws      = (float*)d_ws;
  float* kpre    = ws;                    // [2][8][HW]  = 1048576
  float* halfb   = kpre + 2 * Nn * HWp;   // [2][8][HW]  = 1048576
  float* S       = halfb + 2 * Nn * HWp;  // [2][8][64]  per-channel pixel sums
  unsigned* mxk  = (unsigned*)(S + 1024); // [2][8][64]
  unsigned* kmaxk= mxk + 1024;            // [2][8]
  float* ksum    = (float*)(kmaxk + 16);  // [2][8]
  float* fea     = ksum + 16;             // [2][8][64]
  float* avg     = fea + 1024;            // [2][8][64]
  float* mxs     = avg + 1024;            // [2][8][64]
  float* gate    = mxs + 1024;            // [2][8][64]
  float* vs_arr  = gate + 1024;           // [64]
  float* vb_arr  = vs_arr + 64;           // [64]

  // zero accumulators (S, mxk, kmaxk, ksum, fea are contiguous)
  hipMemsetAsync(S, 0, (size_t)(1024 + 1024 + 16 + 16 + 1024) * sizeof(float), stream);

  dim3 gHeavy(CHUNKS, Nn, 2);   // 1024 blocks
  k1_stats<<<gHeavy, TPB, 0, stream>>>(xrgb, xir, conv_w, conv_b, key_w, key_g, key_b,
                                       key_m, key_v, kpre, mxk, kmaxk);
  k2_ksum<<<dim3(16, 32), TPB, 0, stream>>>(xrgb, xir, kpre, kmaxk, ksum, S);
  k3_fin<<<16, 64, 0, stream>>>(S, mxk, conv_w, conv_b, val_g, val_b, val_m, val_v,
                                avg, mxs, vs_arr, vb_arr);
  k4_val<<<gHeavy, TPB, 0, stream>>>(xrgb, xir, val_w, vs_arr, vb_arr, avg, mxs, kpre,
                                     kmaxk, ksum, half_w, half_g, half_b, half_m, half_v,
                                     halfb, fea);
  k5_gate<<<16, 64, 0, stream>>>(fea, convb_w, ln_g, ln_b, gate);
  k6_out<<<(2 * Nn * Cc * HWp / 4) / 256, 256, 0, stream>>>(xrgb, xir, gate, halfb,
                                                            (float*)d_out);
}

// Round 2
// 882.482 us; speedup vs baseline: 2.1704x; 2.1704x over previous
//
#include <hip/hip_runtime.h>
#include <math.h>

// Problem constants (N,C,H,W) = (8,64,256,256)
constexpr int Nn  = 8;
constexpr int Cc  = 64;
constexpr int HWp = 65536;           // H*W
constexpr int TPB = 256;             // threads per block
constexpr int PPT = 4;               // pixels per thread in heavy kernels
constexpr int PIXB = TPB * PPT;      // 1024 pixels per block
constexpr int CHUNKS = HWp / PIXB;   // 64 -> 1024 blocks for heavy kernels

// ---------- helpers ----------
__device__ inline unsigned fkey(float f) {
  unsigned u = __float_as_uint(f);
  return (u & 0x80000000u) ? ~u : (u | 0x80000000u);  // order-preserving float->uint
}
__device__ inline float funkey(unsigned k) {
  return __uint_as_float((k & 0x80000000u) ? (k & 0x7fffffffu) : ~k);
}
__device__ inline float wmax(float v) {
#pragma unroll
  for (int m = 32; m; m >>= 1) v = fmaxf(v, __shfl_xor(v, m, 64));
  return v;
}
__device__ inline float wsum(float v) {
#pragma unroll
  for (int m = 32; m; m >>= 1) v += __shfl_xor(v, m, 64);
  return v;
}
__device__ inline float silu_(float z) { return z / (1.f + __expf(-z)); }

// ---------- k1: conv stats (max & mean over pixels) + key conv + key exp-sum ----
// Structure: lane <-> pixel; xv[64] (static-indexed) in VGPRs.
// NO per-thread 64-element accumulator arrays: per output channel o, the wave
// reduces its 64 pixels (butterfly) and folds into a SINGLE lane-indexed scalar
// (lane==o). This removes the scratch-resident feap/mx/sms arrays that caused
// ~64KB/block of scratch writes (WRITE_SIZE 74MB) in the previous versions.
__global__ __launch_bounds__(TPB) void k1_stats(
    const float* __restrict__ xrgb, const float* __restrict__ xir,
    const float* __restrict__ conv_w, const float* __restrict__ conv_b,
    const float* __restrict__ key_w, const float* __restrict__ key_g,
    const float* __restrict__ key_b, const float* __restrict__ key_m,
    const float* __restrict__ key_v,
    float* __restrict__ kpre, unsigned* __restrict__ mxk,
    float* __restrict__ smo, float* __restrict__ ksum)
{
  const int side = blockIdx.z, n = blockIdx.y, chunk = blockIdx.x;
  const float* x = (side ? xir : xrgb) + (size_t)n * Cc * HWp;
  const int sn = side * Nn + n;
  const float ks = key_g[0] * rsqrtf(key_v[0] + 1e-5f);
  const float kb = key_b[0] - key_m[0] * ks;
  const int lane = threadIdx.x & 63;

  float mxacc = -1e30f;   // max-over-pixels of conv output, channel o = lane
  float smacc = 0.f;      // sum-over-pixels of conv output, channel o = lane
  float keacc = 0.f;      // sum of exp(key activation) over this lane's pixels

  float* kp = kpre + (size_t)sn * HWp;
  const int e0 = chunk * PIXB + threadIdx.x;
#pragma unroll 1
  for (int i = 0; i < PPT; i++) {
    const int e = e0 + i * TPB;
    float xv[64];
#pragma unroll
    for (int c = 0; c < 64; c++) xv[c] = x[(size_t)c * HWp + e];
    // key conv (1xC) + BN + SiLU ; softmax denom without max-shift (values O(1))
    float kd = 0.f;
#pragma unroll
    for (int c = 0; c < 64; c++) kd += key_w[c] * xv[c];
    float ka = silu_(ks * kd + kb);
    kp[e] = ka;
    keacc += __expf(ka);
    // main conv: per-o compute, wave-reduce over the 64 pixels, fold to lane o
#pragma unroll 4
    for (int o = 0; o < 64; o++) {
      float acc = conv_b[o];
#pragma unroll
      for (int c = 0; c < 64; c++) acc += conv_w[o * 64 + c] * xv[c];
      float m = wmax(acc);
      float s = wsum(acc);
      if (lane == o) { mxacc = fmaxf(mxacc, m); smacc += s; }
    }
  }
  // epilogue: one atomic per lane (accumulators are lane-indexed)
  atomicMax(&mxk[sn * 64 + lane], fkey(mxacc));
  atomicAdd(&smo[sn * 64 + lane], smacc);
  float kes = wsum(keacc);
  if (lane == 0) atomicAdd(&ksum[sn], kes);
}

// ---------- k3: avg/max softmax over channels + val-BN constants ----------
__global__ void k3_fin(const float* __restrict__ smo, const unsigned* __restrict__ mxk,
                       const float* __restrict__ val_g, const float* __restrict__ val_b,
                       const float* __restrict__ val_m, const float* __restrict__ val_v,
                       float* __restrict__ avg, float* __restrict__ mxs,
                       float* __restrict__ vs_arr, float* __restrict__ vb_arr)
{
  const int sn = blockIdx.x, o = threadIdx.x;  // 64 threads = 1 wave
  if (sn == 0) {
    float s = val_g[o] * rsqrtf(val_v[o] + 1e-5f);
    vs_arr[o] = s;
    vb_arr[o] = val_b[o] - val_m[o] * s;
  }
  float lm = smo[sn * 64 + o] * (1.f / HWp);
  float M = wmax(lm);
  float E = __expf(lm - M);
  float S = wsum(E);
  avg[sn * 64 + o] = E / S;
  float mm = funkey(mxk[sn * 64 + o]);
  M = wmax(mm);
  E = __expf(mm - M);
  S = wsum(E);
  mxs[sn * 64 + o] = E / S;
}

// ---------- k4: val conv on-the-fly + fea/avgm/maxm contractions + half ------
// Same lane-indexed-accumulator structure as k1: feap is ONE scalar per thread
// (channel o = lane), folded per-o via wave reduction. No scratch arrays.
__global__ __launch_bounds__(TPB) void k4_val(
    const float* __restrict__ xrgb, const float* __restrict__ xir,
    const float* __restrict__ val_w,
    const float* __restrict__ vs_arr, const float* __restrict__ vb_arr,
    const float* __restrict__ avg, const float* __restrict__ mxs,
    const float* __restrict__ kpre, const float* __restrict__ ksum,
    const float* __restrict__ half_w, const float* __restrict__ half_g,
    const float* __restrict__ half_b, const float* __restrict__ half_m,
    const float* __restrict__ half_v,
    float* __restrict__ halfb, float* __restrict__ fea)
{
  const int me = blockIdx.z, n = blockIdx.y, chunk = blockIdx.x;
  // v comes from the OTHER side's features; stats/key/half/fea belong to `me`
  const float* xo = (me ? xrgb : xir) + (size_t)n * Cc * HWp;
  const int sn = me * Nn + n;
  const float kinv = 1.f / ksum[sn];
  const float* kp = kpre + (size_t)sn * HWp;
  const float hs = half_g[0] * rsqrtf(half_v[0] + 1e-5f);
  const float hb = half_b[0] - half_m[0] * hs;
  const float hw0 = half_w[0], hw1 = half_w[1];
  float* hp = halfb + (size_t)sn * HWp;
  const int lane = threadIdx.x & 63;

  float feap = 0.f;  // sum over pixels of v_o * key-weight, channel o = lane

  const int e0 = chunk * PIXB + threadIdx.x;
#pragma unroll 1
  for (int i = 0; i < PPT; i++) {
    const int e = e0 + i * TPB;
    float xv[64];
#pragma unroll
    for (int c = 0; c < 64; c++) xv[c] = xo[(size_t)c * HWp + e];
    const float kw = __expf(kp[e]) * kinv;   // exp(ka)/sum(exp(ka)) (no shift)
    float am = 0.f, mm = 0.f;
#pragma unroll 4
    for (int o = 0; o < 64; o++) {
      float acc = 0.f;
#pragma unroll
      for (int c = 0; c < 64; c++) acc += val_w[o * 64 + c] * xv[c];
      float v = silu_(vs_arr[o] * acc + vb_arr[o]);
      am += avg[sn * 64 + o] * v;
      mm += mxs[sn * 64 + o] * v;
      float s = wsum(v * kw);
      if (lane == o) feap += s;
    }
    hp[e] = silu_(hs * (hw0 * am + hw1 * mm) + hb);
  }
  atomicAdd(&fea[sn * 64 + lane], feap);
}

// ---------- k5: gate = sigmoid(LN(fea @ convb_w^T)) ----------
__global__ void k5_gate(const float* __restrict__ fea, const float* __restrict__ convb_w,
                        const float* __restrict__ ln_g, const float* __restrict__ ln_b,
                        float* __restrict__ gate)
{
  const int sn = blockIdx.x, o = threadIdx.x;  // 64 threads = 1 wave
  float z = 0.f;
#pragma unroll
  for (int c = 0; c < 64; c++) z += convb_w[o * 64 + c] * fea[sn * 64 + c];
  float mu = wsum(z) * (1.f / 64);
  float d = z - mu;
  float var = wsum(d * d) * (1.f / 64);
  float g = d * rsqrtf(var + 1e-5f) * ln_g[o] + ln_b[o];
  gate[sn * 64 + o] = 1.f / (1.f + __expf(-g));
}

// ---------- k6: out = gate*half + x (streaming, float4) ----------
__global__ __launch_bounds__(256) void k6_out(
    const float* __restrict__ xrgb, const float* __restrict__ xir,
    const float* __restrict__ gate, const float* __restrict__ halfb,
    float* __restrict__ out)
{
  const size_t t = (size_t)blockIdx.x * 256 + threadIdx.x;  // float4 index
  const int e4 = (int)(t & (HWp / 4 - 1));
  size_t r = t >> 14;
  const int c = (int)(r & 63); r >>= 6;
  const int n = (int)(r & 7);
  const int me = (int)(r >> 3);
  const float* x = me ? xir : xrgb;
  const float4 xv = ((const float4*)x)[(((size_t)n * 64 + c) << 14) + e4];
  const float g = gate[(me * 8 + n) * 64 + c];
  const float4 h = ((const float4*)halfb)[((size_t)(me * 8 + n) << 14) + e4];
  float4 ov;
  ov.x = g * h.x + xv.x;
  ov.y = g * h.y + xv.y;
  ov.z = g * h.z + xv.z;
  ov.w = g * h.w + xv.w;
  ((float4*)out)[t] = ov;
}

extern "C" void kernel_launch(void* const* d_in, const int* in_sizes, int n_in,
                              void* d_out, int out_size, void* d_ws, size_t ws_size,
                              hipStream_t stream)
{
  const float* xrgb   = (const float*)d_in[0];
  const float* xir    = (const float*)d_in[1];
  const float* conv_w = (const float*)d_in[2];
  const float* conv_b = (const float*)d_in[3];
  const float* key_w  = (const float*)d_in[4];
  const float* key_g  = (const float*)d_in[5];
  const float* key_b  = (const float*)d_in[6];
  const float* key_m  = (const float*)d_in[7];
  const float* key_v  = (const float*)d_in[8];
  const float* val_w  = (const float*)d_in[9];
  const float* val_g  = (const float*)d_in[10];
  const float* val_b  = (const float*)d_in[11];
  const float* val_m  = (const float*)d_in[12];
  const float* val_v  = (const float*)d_in[13];
  const float* convb_w= (const float*)d_in[14];
  const float* half_w = (const float*)d_in[15];
  const float* half_g = (const float*)d_in[16];
  const float* half_b = (const float*)d_in[17];
  const float* half_m = (const float*)d_in[18];
  const float* half_v = (const float*)d_in[19];
  const float* ln_g   = (const float*)d_in[20];
  const float* ln_b   = (const float*)d_in[21];

  // workspace layout (floats): ~8.4 MiB total
  float* ws      = (float*)d_ws;
  float* kpre    = ws;                    // [2][8][HW]  = 1048576
  float* halfb   = kpre + 2 * Nn * HWp;   // [2][8][HW]  = 1048576
  float* smo     = halfb + 2 * Nn * HWp;  // [2][8][64]  sum over pixels of conv out
  unsigned* mxk  = (unsigned*)(smo + 1024);   // [2][8][64] max keys
  float* ksum    = (float*)(mxk + 1024);  // [2][8]
  float* fea     = ksum + 16;             // [2][8][64]
  float* avg     = fea + 1024;            // [2][8][64]
  float* mxs     = avg + 1024;            // [2][8][64]
  float* gate    = mxs + 1024;            // [2][8][64]
  float* vs_arr  = gate + 1024;           // [64]
  float* vb_arr  = vs_arr + 64;           // [64]

  // zero accumulators (smo, mxk, ksum, fea are contiguous)
  hipMemsetAsync(smo, 0, (size_t)(1024 + 1024 + 16 + 1024) * sizeof(float), stream);

  dim3 gHeavy(CHUNKS, Nn, 2);   // 1024 blocks
  k1_stats<<<gHeavy, TPB, 0, stream>>>(xrgb, xir, conv_w, conv_b, key_w, key_g, key_b,
                                       key_m, key_v, kpre, mxk, smo, ksum);
  k3_fin<<<16, 64, 0, stream>>>(smo, mxk, val_g, val_b, val_m, val_v,
                                avg, mxs, vs_arr, vb_arr);
  k4_val<<<gHeavy, TPB, 0, stream>>>(xrgb, xir, val_w, vs_arr, vb_arr, avg, mxs, kpre,
                                     ksum, half_w, half_g, half_b, half_m, half_v,
                                     halfb, fea);
  k5_gate<<<16, 64, 0, stream>>>(fea, convb_w, ln_g, ln_b, gate);
  k6_out<<<(2 * Nn * Cc * HWp / 4) / 256, 256, 0, stream>>>(xrgb, xir, gate, halfb,
                                                            (float*)d_out);
}

// Round 3
// 715.686 us; speedup vs baseline: 2.6762x; 1.2331x over previous
//
#include <hip/hip_runtime.h>
#include <math.h>

// Problem constants (N,C,H,W) = (8,64,256,256)
constexpr int Nn  = 8;
constexpr int Cc  = 64;
constexpr int HWp = 65536;           // H*W
constexpr int TPB = 256;             // threads per block (4 waves)
constexpr int BPS = 64;              // blocks per (side,n) for heavy kernels
constexpr int WPS = BPS * 4;         // waves per (side,n) = 256
constexpr int PXW = HWp / WPS;       // pixels per wave = 256
constexpr int SPW = PXW / 16;        // 16-pixel strips per wave = 16

typedef _Float16 f16;
typedef _Float16 f16x8 __attribute__((ext_vector_type(8)));
typedef float    f32x4 __attribute__((ext_vector_type(4)));

// ---------- helpers ----------
__device__ inline unsigned fkey(float f) {
  unsigned u = __float_as_uint(f);
  return (u & 0x80000000u) ? ~u : (u | 0x80000000u);  // order-preserving float->uint
}
__device__ inline float funkey(unsigned k) {
  return __uint_as_float((k & 0x80000000u) ? (k & 0x7fffffffu) : ~k);
}
__device__ inline float wmax(float v) {
#pragma unroll
  for (int m = 32; m; m >>= 1) v = fmaxf(v, __shfl_xor(v, m, 64));
  return v;
}
__device__ inline float wsum(float v) {
#pragma unroll
  for (int m = 32; m; m >>= 1) v += __shfl_xor(v, m, 64);
  return v;
}
__device__ inline float silu_(float z) { return z / (1.f + __expf(-z)); }

// ==========================================================================
// k1: conv1x1 as MFMA (f16 in, fp32 acc), max+sum over pixels accumulated in
// fragment layout; key conv + exp-sum ride along in VALU.
// Per wave-step: 16 pixels x 64 channels = 8 x mfma_f32_16x16x32_f16.
// B frags load DIRECTLY from global (no LDS): lane reads
// x[c = 32*k0 + 8*(lane>>4) + j][e0 + (lane&15)] — contiguous 64B per
// 16-lane group. A (weights) and B use the same k-chunk map (lane>>4), so
// the contraction is layout-permutation-invariant; only the C/D layout
// (col=lane&15 -> pixel, row=(lane>>4)*4+reg -> channel) is load-bearing.
// conv_b folded into k3 (max/sum commute with per-o constant).
// ==========================================================================
__global__ __launch_bounds__(TPB) void k1_stats(
    const float* __restrict__ xrgb, const float* __restrict__ xir,
    const float* __restrict__ conv_w,
    const float* __restrict__ key_w, const float* __restrict__ key_g,
    const float* __restrict__ key_b, const float* __restrict__ key_m,
    const float* __restrict__ key_v,
    float* __restrict__ kpre, unsigned* __restrict__ mxk,
    float* __restrict__ smo, float* __restrict__ ksum)
{
  const int side = blockIdx.z, n = blockIdx.y, blk = blockIdx.x;
  const int wv = threadIdx.x >> 6, lane = threadIdx.x & 63;
  const int lh = lane >> 4, lc = lane & 15;
  const int sn = side * Nn + n;
  const float* x = (side ? xir : xrgb) + (size_t)n * Cc * HWp;
  const float ks = key_g[0] * rsqrtf(key_v[0] + 1e-5f);
  const float kb = key_b[0] - key_m[0] * ks;
  float* kp = kpre + (size_t)sn * HWp;

  // A fragments: conv_w row = 16*ob + lc, k = 32*k0 + 8*lh + j
  f16x8 A[4][2];
#pragma unroll
  for (int ob = 0; ob < 4; ob++)
#pragma unroll
    for (int k0 = 0; k0 < 2; k0++) {
      const float* wr = conv_w + (16 * ob + lc) * 64 + 32 * k0 + 8 * lh;
      float4 w0 = ((const float4*)wr)[0], w1 = ((const float4*)wr)[1];
      A[ob][k0] = (f16x8){(f16)w0.x, (f16)w0.y, (f16)w0.z, (f16)w0.w,
                          (f16)w1.x, (f16)w1.y, (f16)w1.z, (f16)w1.w};
    }
  // key weights with the same k-chunk mapping (consumed from the fp32 loads)
  float kw0[2][8];
#pragma unroll
  for (int k0 = 0; k0 < 2; k0++) {
    const float* wr = key_w + 32 * k0 + 8 * lh;
    float4 w0 = ((const float4*)wr)[0], w1 = ((const float4*)wr)[1];
    kw0[k0][0] = w0.x; kw0[k0][1] = w0.y; kw0[k0][2] = w0.z; kw0[k0][3] = w0.w;
    kw0[k0][4] = w1.x; kw0[k0][5] = w1.y; kw0[k0][6] = w1.z; kw0[k0][7] = w1.w;
  }

  f32x4 mxf[4], smf[4];
#pragma unroll
  for (int ob = 0; ob < 4; ob++) {
    mxf[ob] = (f32x4){-1e30f, -1e30f, -1e30f, -1e30f};
    smf[ob] = (f32x4){0.f, 0.f, 0.f, 0.f};
  }
  float keacc = 0.f;

  const int base = (blk * 4 + wv) * PXW;
#pragma unroll 1
  for (int s = 0; s < SPW; s++) {
    const int e = base + s * 16 + lc;
    f16x8 B[2];
    float keyp = 0.f;
#pragma unroll
    for (int k0 = 0; k0 < 2; k0++)
#pragma unroll
      for (int j = 0; j < 8; j++) {
        float xf = x[(size_t)(32 * k0 + 8 * lh + j) * HWp + e];
        B[k0][j] = (f16)xf;
        keyp += kw0[k0][j] * xf;
      }
    keyp += __shfl_xor(keyp, 16, 64);
    keyp += __shfl_xor(keyp, 32, 64);
    if (lh == 0) {
      float ka = silu_(ks * keyp + kb);
      kp[e] = ka;
      keacc += __expf(ka);   // no max-shift: values O(1) (proven in prior round)
    }
#pragma unroll
    for (int ob = 0; ob < 4; ob++) {
      f32x4 t = (f32x4){0.f, 0.f, 0.f, 0.f};
      t = __builtin_amdgcn_mfma_f32_16x16x32_f16(A[ob][0], B[0], t, 0, 0, 0);
      t = __builtin_amdgcn_mfma_f32_16x16x32_f16(A[ob][1], B[1], t, 0, 0, 0);
#pragma unroll
      for (int r = 0; r < 4; r++) {
        mxf[ob][r] = fmaxf(mxf[ob][r], t[r]);
        smf[ob][r] += t[r];
      }
    }
  }
  // epilogue: reduce over the 16 pixel-columns, one atomic set per wave
#pragma unroll
  for (int ob = 0; ob < 4; ob++)
#pragma unroll
    for (int r = 0; r < 4; r++) {
      float m = mxf[ob][r], sv = smf[ob][r];
#pragma unroll
      for (int msk = 1; msk < 16; msk <<= 1) {
        m = fmaxf(m, __shfl_xor(m, msk, 64));
        sv += __shfl_xor(sv, msk, 64);
      }
      if (lc == 0) {
        const int o = 16 * ob + 4 * lh + r;
        atomicMax(&mxk[sn * 64 + o], fkey(m));
        atomicAdd(&smo[sn * 64 + o], sv);
      }
    }
  float ke = keacc;
#pragma unroll
  for (int msk = 1; msk < 64; msk <<= 1) ke += __shfl_xor(ke, msk, 64);
  if (lane == 0) atomicAdd(&ksum[sn], ke);
}

// ---------- k3: avg/max softmax over channels (+conv_b bias) + val-BN consts --
__global__ void k3_fin(const float* __restrict__ smo, const unsigned* __restrict__ mxk,
                       const float* __restrict__ conv_b,
                       const float* __restrict__ val_g, const float* __restrict__ val_b,
                       const float* __restrict__ val_m, const float* __restrict__ val_v,
                       float* __restrict__ avg, float* __restrict__ mxs,
                       float* __restrict__ vs_arr, float* __restrict__ vb_arr)
{
  const int sn = blockIdx.x, o = threadIdx.x;  // 64 threads = 1 wave
  if (sn == 0) {
    float s = val_g[o] * rsqrtf(val_v[o] + 1e-5f);
    vs_arr[o] = s;
    vb_arr[o] = val_b[o] - val_m[o] * s;
  }
  const float cb = conv_b[o];
  float lm = cb + smo[sn * 64 + o] * (1.f / HWp);
  float M = wmax(lm);
  float E = __expf(lm - M);
  float S = wsum(E);
  avg[sn * 64 + o] = E / S;
  float mm = cb + funkey(mxk[sn * 64 + o]);
  M = wmax(mm);
  E = __expf(mm - M);
  S = wsum(E);
  mxs[sn * 64 + o] = E / S;
}

// ==========================================================================
// k4: val conv via MFMA + fea/avgm/maxm contractions + half. Same geometry
// as k1. Per-o constants (vs,vb,avg,mxs) preloaded in fragment order.
// ==========================================================================
__global__ __launch_bounds__(TPB) void k4_val(
    const float* __restrict__ xrgb, const float* __restrict__ xir,
    const float* __restrict__ val_w,
    const float* __restrict__ vs_arr, const float* __restrict__ vb_arr,
    const float* __restrict__ avg, const float* __restrict__ mxs,
    const float* __restrict__ kpre, const float* __restrict__ ksum,
    const float* __restrict__ half_w, const float* __restrict__ half_g,
    const float* __restrict__ half_b, const float* __restrict__ half_m,
    const float* __restrict__ half_v,
    float* __restrict__ halfb, float* __restrict__ fea)
{
  const int me = blockIdx.z, n = blockIdx.y, blk = blockIdx.x;
  const int wv = threadIdx.x >> 6, lane = threadIdx.x & 63;
  const int lh = lane >> 4, lc = lane & 15;
  const int sn = me * Nn + n;
  // v comes from the OTHER side's features; stats/key/half/fea belong to `me`
  const float* xo = (me ? xrgb : xir) + (size_t)n * Cc * HWp;
  const float kinv = 1.f / ksum[sn];
  const float* kp = kpre + (size_t)sn * HWp;
  const float hs = half_g[0] * rsqrtf(half_v[0] + 1e-5f);
  const float hb = half_b[0] - half_m[0] * hs;
  const float hw0 = half_w[0], hw1 = half_w[1];
  float* hp = halfb + (size_t)sn * HWp;

  f16x8 A[4][2];
#pragma unroll
  for (int ob = 0; ob < 4; ob++)
#pragma unroll
    for (int k0 = 0; k0 < 2; k0++) {
      const float* wr = val_w + (16 * ob + lc) * 64 + 32 * k0 + 8 * lh;
      float4 w0 = ((const float4*)wr)[0], w1 = ((const float4*)wr)[1];
      A[ob][k0] = (f16x8){(f16)w0.x, (f16)w0.y, (f16)w0.z, (f16)w0.w,
                          (f16)w1.x, (f16)w1.y, (f16)w1.z, (f16)w1.w};
    }
  // per-o constants in fragment order: o = 16*ob + 4*lh + r
  float vsl[4][4], vbl[4][4], avl[4][4], mxl[4][4];
#pragma unroll
  for (int ob = 0; ob < 4; ob++)
#pragma unroll
    for (int r = 0; r < 4; r++) {
      const int o = 16 * ob + 4 * lh + r;
      vsl[ob][r] = vs_arr[o];
      vbl[ob][r] = vb_arr[o];
      avl[ob][r] = avg[sn * 64 + o];
      mxl[ob][r] = mxs[sn * 64 + o];
    }
  f32x4 feaf[4];
#pragma unroll
  for (int ob = 0; ob < 4; ob++) feaf[ob] = (f32x4){0.f, 0.f, 0.f, 0.f};

  const int base = (blk * 4 + wv) * PXW;
#pragma unroll 1
  for (int s = 0; s < SPW; s++) {
    const int e = base + s * 16 + lc;
    f16x8 B[2];
#pragma unroll
    for (int k0 = 0; k0 < 2; k0++)
#pragma unroll
      for (int j = 0; j < 8; j++)
        B[k0][j] = (f16)xo[(size_t)(32 * k0 + 8 * lh + j) * HWp + e];
    const float kwv = __expf(kp[e]) * kinv;
    float am = 0.f, mm = 0.f;
#pragma unroll
    for (int ob = 0; ob < 4; ob++) {
      f32x4 t = (f32x4){0.f, 0.f, 0.f, 0.f};
      t = __builtin_amdgcn_mfma_f32_16x16x32_f16(A[ob][0], B[0], t, 0, 0, 0);
      t = __builtin_amdgcn_mfma_f32_16x16x32_f16(A[ob][1], B[1], t, 0, 0, 0);
#pragma unroll
      for (int r = 0; r < 4; r++) {
        float v = silu_(vsl[ob][r] * t[r] + vbl[ob][r]);
        am += avl[ob][r] * v;
        mm += mxl[ob][r] * v;
        feaf[ob][r] += v * kwv;
      }
    }
    am += __shfl_xor(am, 16, 64); am += __shfl_xor(am, 32, 64);
    mm += __shfl_xor(mm, 16, 64); mm += __shfl_xor(mm, 32, 64);
    if (lh == 0) hp[e] = silu_(hs * (hw0 * am + hw1 * mm) + hb);
  }
  // epilogue: reduce fea over 16 pixel-columns, one atomic per (o)
#pragma unroll
  for (int ob = 0; ob < 4; ob++)
#pragma unroll
    for (int r = 0; r < 4; r++) {
      float sv = feaf[ob][r];
#pragma unroll
      for (int msk = 1; msk < 16; msk <<= 1) sv += __shfl_xor(sv, msk, 64);
      if (lc == 0) atomicAdd(&fea[sn * 64 + 16 * ob + 4 * lh + r], sv);
    }
}

// ---------- k5: gate = sigmoid(LN(fea @ convb_w^T)) ----------
__global__ void k5_gate(const float* __restrict__ fea, const float* __restrict__ convb_w,
                        const float* __restrict__ ln_g, const float* __restrict__ ln_b,
                        float* __restrict__ gate)
{
  const int sn = blockIdx.x, o = threadIdx.x;  // 64 threads = 1 wave
  float z = 0.f;
#pragma unroll
  for (int c = 0; c < 64; c++) z += convb_w[o * 64 + c] * fea[sn * 64 + c];
  float mu = wsum(z) * (1.f / 64);
  float d = z - mu;
  float var = wsum(d * d) * (1.f / 64);
  float g = d * rsqrtf(var + 1e-5f) * ln_g[o] + ln_b[o];
  gate[sn * 64 + o] = 1.f / (1.f + __expf(-g));
}

// ---------- k6: out = gate*half + x (streaming, float4) ----------
__global__ __launch_bounds__(256) void k6_out(
    const float* __restrict__ xrgb, const float* __restrict__ xir,
    const float* __restrict__ gate, const float* __restrict__ halfb,
    float* __restrict__ out)
{
  const size_t t = (size_t)blockIdx.x * 256 + threadIdx.x;  // float4 index
  const int e4 = (int)(t & (HWp / 4 - 1));
  size_t r = t >> 14;
  const int c = (int)(r & 63); r >>= 6;
  const int n = (int)(r & 7);
  const int me = (int)(r >> 3);
  const float* x = me ? xir : xrgb;
  const float4 xv = ((const float4*)x)[(((size_t)n * 64 + c) << 14) + e4];
  const float g = gate[(me * 8 + n) * 64 + c];
  const float4 h = ((const float4*)halfb)[((size_t)(me * 8 + n) << 14) + e4];
  float4 ov;
  ov.x = g * h.x + xv.x;
  ov.y = g * h.y + xv.y;
  ov.z = g * h.z + xv.z;
  ov.w = g * h.w + xv.w;
  ((float4*)out)[t] = ov;
}

extern "C" void kernel_launch(void* const* d_in, const int* in_sizes, int n_in,
                              void* d_out, int out_size, void* d_ws, size_t ws_size,
                              hipStream_t stream)
{
  const float* xrgb   = (const float*)d_in[0];
  const float* xir    = (const float*)d_in[1];
  const float* conv_w = (const float*)d_in[2];
  const float* conv_b = (const float*)d_in[3];
  const float* key_w  = (const float*)d_in[4];
  const float* key_g  = (const float*)d_in[5];
  const float* key_b  = (const float*)d_in[6];
  const float* key_m  = (const float*)d_in[7];
  const float* key_v  = (const float*)d_in[8];
  const float* val_w  = (const float*)d_in[9];
  const float* val_g  = (const float*)d_in[10];
  const float* val_b  = (const float*)d_in[11];
  const float* val_m  = (const float*)d_in[12];
  const float* val_v  = (const float*)d_in[13];
  const float* convb_w= (const float*)d_in[14];
  const float* half_w = (const float*)d_in[15];
  const float* half_g = (const float*)d_in[16];
  const float* half_b = (const float*)d_in[17];
  const float* half_m = (const float*)d_in[18];
  const float* half_v = (const float*)d_in[19];
  const float* ln_g   = (const float*)d_in[20];
  const float* ln_b   = (const float*)d_in[21];

  // workspace layout (floats): ~8.4 MiB total
  float* ws      = (float*)d_ws;
  float* kpre    = ws;                    // [2][8][HW]  = 1048576
  float* halfb   = kpre + 2 * Nn * HWp;   // [2][8][HW]  = 1048576
  float* smo     = halfb + 2 * Nn * HWp;  // [2][8][64]  sum over pixels (no bias)
  unsigned* mxk  = (unsigned*)(smo + 1024);   // [2][8][64] max keys (no bias)
  float* ksum    = (float*)(mxk + 1024);  // [2][8]
  float* fea     = ksum + 16;             // [2][8][64]
  float* avg     = fea + 1024;            // [2][8][64]
  float* mxs     = avg + 1024;            // [2][8][64]
  float* gate    = mxs + 1024;            // [2][8][64]
  float* vs_arr  = gate + 1024;           // [64]
  float* vb_arr  = vs_arr + 64;           // [64]

  // zero accumulators (smo, mxk, ksum, fea are contiguous)
  hipMemsetAsync(smo, 0, (size_t)(1024 + 1024 + 16 + 1024) * sizeof(float), stream);

  dim3 gHeavy(BPS, Nn, 2);   // 1024 blocks, 4 independent waves each
  k1_stats<<<gHeavy, TPB, 0, stream>>>(xrgb, xir, conv_w, key_w, key_g, key_b,
                                       key_m, key_v, kpre, mxk, smo, ksum);
  k3_fin<<<16, 64, 0, stream>>>(smo, mxk, conv_b, val_g, val_b, val_m, val_v,
                                avg, mxs, vs_arr, vb_arr);
  k4_val<<<gHeavy, TPB, 0, stream>>>(xrgb, xir, val_w, vs_arr, vb_arr, avg, mxs, kpre,
                                     ksum, half_w, half_g, half_b, half_m, half_v,
                                     halfb, fea);
  k5_gate<<<16, 64, 0, stream>>>(fea, convb_w, ln_g, ln_b, gate);
  k6_out<<<(2 * Nn * Cc * HWp / 4) / 256, 256, 0, stream>>>(xrgb, xir, gate, halfb,
                                                            (float*)d_out);
}